// Round 13
// baseline (404.353 us; speedup 1.0000x reference)
//
#include <hip/hip_runtime.h>
#include <hip/hip_bf16.h>

#define EMBED 1024
#define HEADS 16
#define HDIM 64
#define BATCH 4
#define SEQ 2048
#define ROWS (BATCH * SEQ) /* 8192 */
#define LOG2E 1.4426950408889634f

typedef __attribute__((ext_vector_type(8))) short bf16x8;  // 8 bf16 = 4 VGPRs
typedef __attribute__((ext_vector_type(4))) float f32x4;   // MFMA 16x16 acc

#define MFMA16(a, b, c) __builtin_amdgcn_mfma_f32_16x16x32_bf16(a, b, c, 0, 0, 0)

__device__ __forceinline__ unsigned short f2bf(float f) {
    union { float f; unsigned int u; } x; x.f = f;
    unsigned int r = x.u + 0x7fffu + ((x.u >> 16) & 1u); // RNE
    return (unsigned short)(r >> 16);
}

// packed (a,b) -> 2x bf16 in one dword; HW v_cvt_pk_bf16_f32 when available
__device__ __forceinline__ unsigned int pkbf(float a, float b) {
#if __has_builtin(__builtin_amdgcn_cvt_pk_bf16_f32)
    auto v = __builtin_amdgcn_cvt_pk_bf16_f32(a, b);
    unsigned int u; __builtin_memcpy(&u, &v, 4); return u;
#else
    union { __hip_bfloat162 h; unsigned int u; } c;
    c.h = __float22bfloat162_rn(make_float2(a, b)); return c.u;
#endif
}

// async global->LDS, 16 B per lane; lds dest = wave-uniform base + lane*16
__device__ __forceinline__ void gl2lds(const unsigned short* g, unsigned short* l) {
    __builtin_amdgcn_global_load_lds(
        (const __attribute__((address_space(1))) unsigned int*)g,
        (__attribute__((address_space(3))) unsigned int*)l, 16, 0, 0);
}

// ---------------------------------------------------------------------------
// Fused prep: [0,8192) cvt_x | [8192,24576) cvt_mask | [24576,28672) wtrans
// ---------------------------------------------------------------------------
#define XBLK 8192
#define MBLK 16384
#define WBLK 4096

__global__ __launch_bounds__(256) void prep_kernel(
    const float* __restrict__ x, const int* __restrict__ mask,
    const float* __restrict__ W0, const float* __restrict__ W1,
    const float* __restrict__ W2, const float* __restrict__ W3,
    unsigned short* __restrict__ Xb, unsigned char* __restrict__ m8,
    unsigned short* __restrict__ Wt)
{
    __shared__ float t[32][33];
    const int bid = blockIdx.x;
    if (bid < XBLK) {
        int i = (bid * 256 + threadIdx.x) * 4;
        float4 v = *(const float4*)(x + i);
        uint2 o; o.x = pkbf(v.x, v.y); o.y = pkbf(v.z, v.w);
        *(uint2*)(Xb + i) = o;
    } else if (bid < XBLK + MBLK) {
        int i = ((bid - XBLK) * 256 + threadIdx.x) * 4;
        int4 v = *(const int4*)(mask + i);
        uchar4 o;
        o.x = v.x ? 0xFF : 0; o.y = v.y ? 0xFF : 0;
        o.z = v.z ? 0xFF : 0; o.w = v.w ? 0xFF : 0;
        *(uchar4*)(m8 + i) = o;
    } else {
        int f = bid - XBLK - MBLK;           // 0..4095
        int z = f >> 10, rem = f & 1023;
        const float* W = (z == 0) ? W0 : (z == 1) ? W1 : (z == 2) ? W2 : W3;
        unsigned short* o = Wt + (size_t)z * EMBED * EMBED;
        int tx = threadIdx.x & 31, ty = threadIdx.x >> 5;
        int bx = (rem & 31) * 32, by = (rem >> 5) * 32;  // bx: n, by: k
#pragma unroll
        for (int r = 0; r < 32; r += 8)
            t[ty + r][tx] = W[(size_t)(by + ty + r) * EMBED + bx + tx];
        __syncthreads();
#pragma unroll
        for (int r = 0; r < 32; r += 8)
            o[(size_t)(bx + ty + r) * EMBED + by + tx] = f2bf(t[tx][ty + r]);
    }
}

// ---------------------------------------------------------------------------
// bf16 MFMA GEMM: EXACT R8 single-buffered body (best measured config).
// 128x128 tile, BK=64, unpadded XOR-swizzled LDS (128-B rows, phys_chunk =
// logical ^ (row&7)); staged via gl2lds with per-lane swizzled SOURCE
// addresses. 4 waves, 4x4 16x16x32. m0/n0 passed in (XCD swizzle).
// R12 NOTE: explicit double-buffer regressed (-11 us): dynamic buffer index
// As[t] defeats LDS alias analysis (conservative vmcnt wait before ds_reads)
// and 64 KB LDS halves occupancy 5->2 blocks/CU. Single buffer + implicit
// cross-block overlap is the measured optimum for this structure.
// vmode=1: V projection writes output transposed to Vt[b][h][d][kseq].
// ---------------------------------------------------------------------------
__device__ __forceinline__ void gemm_bf16_body(
    const unsigned short* __restrict__ A, const unsigned short* __restrict__ Bt,
    const float* __restrict__ bias,
    float* __restrict__ outF, unsigned short* __restrict__ outB, float scale,
    int vmode, int m0, int n0)
{
    __shared__ unsigned short As[128][64]; // 16 KB
    __shared__ unsigned short Bs[128][64]; // 16 KB
    const int tid = threadIdx.x;
    const int lane = tid & 63, wid = tid >> 6;
    const int ln = lane & 15, lg = lane >> 4;
    const int wy = wid >> 1, wx = wid & 1;
    // staging: lane stages row r0(+8*is), phys chunk = lane&7,
    // swizzled source logical chunk = (lane&7) ^ (r&7), r&7 = lane>>3
    const int r0 = wid * 32 + (lane >> 3);
    const int scol = (((lane & 7) ^ ((lane >> 3) & 7)) << 3);
    const unsigned short* Ap = A + (size_t)(m0 + r0) * EMBED + scol;
    const unsigned short* Bp = Bt + (size_t)(n0 + r0) * EMBED + scol;
    unsigned short* lA = &As[wid * 32][0]; // wave-uniform
    unsigned short* lB = &Bs[wid * 32][0];

    f32x4 acc[4][4];
#pragma unroll
    for (int i = 0; i < 4; i++)
#pragma unroll
        for (int j = 0; j < 4; j++) acc[i][j] = (f32x4){0.f, 0.f, 0.f, 0.f};

    for (int k0 = 0; k0 < EMBED; k0 += 64) {
        __syncthreads();
#pragma unroll
        for (int is = 0; is < 4; is++) {
            gl2lds(Ap + k0 + (size_t)(is * 8) * EMBED, lA + is * 8 * 64);
            gl2lds(Bp + k0 + (size_t)(is * 8) * EMBED, lB + is * 8 * 64);
        }
        __syncthreads();
        bf16x8 af[2][4], bfr[2][4];
#pragma unroll
        for (int s = 0; s < 2; s++) {
#pragma unroll
            for (int mi = 0; mi < 4; mi++)
                af[s][mi] = *(const bf16x8*)
                    &As[wy * 64 + mi * 16 + ln][(((lg + 4 * s) ^ (ln & 7)) << 3)];
#pragma unroll
            for (int nj = 0; nj < 4; nj++)
                bfr[s][nj] = *(const bf16x8*)
                    &Bs[wx * 64 + nj * 16 + ln][(((lg + 4 * s) ^ (ln & 7)) << 3)];
        }
#pragma unroll
        for (int s = 0; s < 2; s++)
#pragma unroll
            for (int mi = 0; mi < 4; mi++)
#pragma unroll
                for (int nj = 0; nj < 4; nj++)
                    acc[mi][nj] = MFMA16(af[s][mi], bfr[s][nj], acc[mi][nj]);
    }

#pragma unroll
    for (int mi = 0; mi < 4; mi++) {
#pragma unroll
        for (int nj = 0; nj < 4; nj++) {
            int row = m0 + wy * 64 + mi * 16 + lg * 4;
            int col = n0 + wx * 64 + nj * 16 + ln;
            float bv = bias[col];
            if (vmode) {
                // V output: Vt[(b*HEADS+h)*HDIM + d][s], 4 consecutive s/lane
                int bb = row >> 11, s = row & (SEQ - 1);
                int hh = col >> 6, dd = col & 63;
                unsigned short* dst = outB +
                    ((size_t)((bb * HEADS + hh) * HDIM + dd)) * SEQ + s;
                uint2 pw;
                pw.x = pkbf(acc[mi][nj][0] + bv, acc[mi][nj][1] + bv);
                pw.y = pkbf(acc[mi][nj][2] + bv, acc[mi][nj][3] + bv);
                *(uint2*)dst = pw;
            } else {
#pragma unroll
                for (int r = 0; r < 4; r++) {
                    float v = (acc[mi][nj][r] + bv) * scale;
                    if (outF) outF[(size_t)(row + r) * EMBED + col] = v;
                    else      outB[(size_t)(row + r) * EMBED + col] = f2bf(v);
                }
            }
        }
    }
}

// qkv: 1-D grid of 1536 with XCD-aware decode (R6: each XCD gets a
// contiguous 8-strip m-chunk; A working set 2 MB fits its 4 MB L2).
__global__ __launch_bounds__(256) void qkv_gemm_kernel(
    const unsigned short* __restrict__ Xb, const unsigned short* __restrict__ Wt,
    const float* __restrict__ bq, const float* __restrict__ bk,
    const float* __restrict__ bv,
    unsigned short* __restrict__ Qb, unsigned short* __restrict__ Kb,
    unsigned short* __restrict__ Vt)
{
    const int bid = blockIdx.x;
    const int xcd = bid & 7;
    const int idx = bid >> 3;        // 0..191
    const int bx  = idx & 7;         // N-block 0..7
    const int yi  = (idx >> 3) & 7;  // 0..7
    const int z   = idx >> 6;        // 0..2
    const int by  = xcd * 8 + yi;    // M-block 0..63

    const unsigned short* Bt = Wt + (size_t)z * EMBED * EMBED;
    const float* bias = (z == 0) ? bq : (z == 1) ? bk : bv;
    unsigned short* out = (z == 0) ? Qb : (z == 1) ? Kb : Vt;
    // fold 1/sqrt(HDIM) AND log2(e) into Q so softmax uses raw v_exp_f32
    float scale = (z == 0) ? 0.125f * LOG2E : 1.0f;
    gemm_bf16_body(Xb, Bt, bias, nullptr, out, scale, z == 2,
                   by * 128, bx * 128);
}

// out: 1-D grid of 512, same XCD decode (8*8*8=512 bijective).
__global__ __launch_bounds__(256) void out_gemm_kernel(
    const unsigned short* __restrict__ Ob, const unsigned short* __restrict__ Wto,
    const float* __restrict__ bo, float* __restrict__ out)
{
    const int bid = blockIdx.x;
    const int xcd = bid & 7;
    const int idx = bid >> 3;        // 0..63
    const int bx  = idx & 7;
    const int yi  = idx >> 3;        // 0..7
    const int by  = xcd * 8 + yi;    // 0..63
    gemm_bf16_body(Ob, Wto, bo, out, nullptr, 1.0f, 0, by * 128, bx * 128);
}

// ---------------------------------------------------------------------------
// Flash attention, bf16 MFMA, no-max softmax. R8 kernel (best measured:
// 159.6 us) -- in-register P via sigma-permutation, sigma-permuted V in LDS,
// XCD-aware (b,h) decode -- plus T5 s_setprio(1/0) around the MFMA clusters
// (R13). Mechanism: 4 independent blocks/CU drift out of barrier phase; a
// wave entering its MFMA cluster wins scheduler arbitration over other
// blocks' staging waves (m191-positive regime: cross-block, not lockstep).
// Dataflow otherwise frozen after R9/R10 refuted restructuring.
// ---------------------------------------------------------------------------
__global__ __launch_bounds__(256) void attn_mfma_kernel(
    const unsigned short* __restrict__ Qb, const unsigned short* __restrict__ Kb,
    const unsigned short* __restrict__ Vt, const unsigned char* __restrict__ mask8,
    unsigned short* __restrict__ Ob)
{
    __shared__ unsigned short Ks[64][64];    // [kseq][d]     8 KB (swizzled)
    __shared__ unsigned short Vs[64][64];    // [d][sigma(k)]  8 KB (swizzled)
    const int tid = threadIdx.x;
    const int lane = tid & 63, wid = tid >> 6;
    const int ln = lane & 15, lg = lane >> 4;

    // XCD decode: xcd owns bh in [xcd*8, xcd*8+8), all 16 q-blocks each
    const int bid = blockIdx.x;
    const int xcd = bid & 7;
    const int i5 = bid >> 3;         // 0..127
    const int qx = i5 & 15;          // q-block 0..15
    const int bh = xcd * 8 + (i5 >> 4);
    const int h = bh & 15, b = bh >> 4;
    const int q0 = qx * 128 + wid * 32;

    bf16x8 qf[2][2]; // B-frag: row q0+mi*16+ln, d = ks*32+lg*8..
#pragma unroll
    for (int mi = 0; mi < 2; mi++)
#pragma unroll
        for (int ks = 0; ks < 2; ks++)
            qf[mi][ks] = *(const bf16x8*)(Qb +
                (size_t)(b * SEQ + q0 + mi * 16 + ln) * EMBED + h * HDIM + ks * 32 + lg * 8);

    bf16x8 ones;
#pragma unroll
    for (int i = 0; i < 8; i++) ones[i] = (short)0x3F80; // bf16 1.0

    f32x4 o[2][4];
#pragma unroll
    for (int mi = 0; mi < 2; mi++)
#pragma unroll
        for (int dj = 0; dj < 4; dj++) o[mi][dj] = (f32x4){0.f, 0.f, 0.f, 0.f};
    f32x4 lacc[2] = {(f32x4){0.f, 0.f, 0.f, 0.f}, (f32x4){0.f, 0.f, 0.f, 0.f}};

    // K staging (gl2lds): srow = tid>>3, source chunk = (tid&7)^(srow&7)
    const int srow = tid >> 3;
    const int scolK = (((tid & 7) ^ ((tid >> 3) & 7)) << 3);
    const unsigned short* Kp = Kb + (size_t)(b * SEQ + srow) * EMBED + h * HDIM + scolK;
    unsigned short* lK = &Ks[srow & ~7][0]; // wave-uniform

    // V reg-staging (sigma-permuted): thread (vrow = tid>>2, vu = tid&3)
    // writes dest chunks c = vu and vu+4 of row vrow. Chunk c holds tile
    // positions 8c..8c+7 = values V[row][32(c>>2) + 4(c&3) + (j&3) + 16(j>>2)]
    // -> two 8-B granules at kseq 4(c&3)+32(c>>2) and +16. Loads for both
    // chunks: kt + 4*vu + {0,16,32,48} shorts. Phys chunk = c ^ (vrow&7).
    const int vrow = tid >> 2, vu = tid & 3;
    const unsigned short* Vp = Vt + (size_t)((b * HEADS + h) * HDIM + vrow) * SEQ + 4 * vu;
    unsigned short* vdst = &Vs[vrow][0];
    const int vw0 = ((vu ^ (vrow & 7)) << 3);
    const int vw1 = (((vu + 4) ^ (vrow & 7)) << 3);

    const unsigned char* mq0 = mask8 + (size_t)b * SEQ * SEQ + (size_t)(q0 + ln) * SEQ;
    const unsigned char* mq1 = mq0 + (size_t)16 * SEQ;

    // swizzled fragment-read columns
    const int swk = ((lg ^ (ln & 7)) << 3);            // Ks (QK^T)
    int vrd[2];                                         // Vs (PV), per ks
#pragma unroll
    for (int ks = 0; ks < 2; ks++)
        vrd[ks] = ((4 * ks + lg) ^ (ln & 7)) << 3;

    union U8 { bf16x8 v; unsigned int w[4]; };

    for (int kt = 0; kt < SEQ; kt += 64) {
        // mask loads: independent of LDS, overlap barrier waits
        unsigned int mw[2][4];
#pragma unroll
        for (int mi = 0; mi < 2; mi++) {
            const unsigned char* mq = (mi ? mq1 : mq0) + kt;
#pragma unroll
            for (int nj = 0; nj < 4; nj++)
                mw[mi][nj] = *(const unsigned int*)(mq + nj * 16 + lg * 4);
        }

        // V tile loads to regs (read-only global; no barrier hazard)
        uint2 v0 = *(const uint2*)(Vp + kt);
        uint2 v1 = *(const uint2*)(Vp + kt + 16);
        uint2 v2 = *(const uint2*)(Vp + kt + 32);
        uint2 v3 = *(const uint2*)(Vp + kt + 48);

        __syncthreads(); // previous tile fully consumed
        gl2lds(Kp + (size_t)kt * EMBED, lK);
        gl2lds(Kp + (size_t)(kt + 32) * EMBED, lK + 32 * 64);
        {
            uint4 w0; w0.x = v0.x; w0.y = v0.y; w0.z = v1.x; w0.w = v1.y;
            uint4 w1; w1.x = v2.x; w1.y = v2.y; w1.z = v3.x; w1.w = v3.y;
            *(uint4*)(vdst + vw0) = w0;
            *(uint4*)(vdst + vw1) = w1;
        }
        __syncthreads(); // DMA + V writes drained

        // S^T: rows = kseq (nj*16+lg*4+reg), cols = q (mi*16+ln)
        f32x4 S[2][4];
        __builtin_amdgcn_s_setprio(1);
#pragma unroll
        for (int nj = 0; nj < 4; nj++) {
            bf16x8 k0 = *(const bf16x8*)&Ks[nj * 16 + ln][swk];
            bf16x8 k1 = *(const bf16x8*)&Ks[nj * 16 + ln][swk ^ 32];
#pragma unroll
            for (int mi = 0; mi < 2; mi++) {
                f32x4 t2 = (f32x4){0.f, 0.f, 0.f, 0.f};
                t2 = MFMA16(k0, qf[mi][0], t2);
                t2 = MFMA16(k1, qf[mi][1], t2);
                S[mi][nj] = t2;
            }
        }
        __builtin_amdgcn_s_setprio(0);

        // exp2 + packed cvt + mask-AND, assembled directly into PV A-frags
        // (sigma order; HW-verified). Frag (mi,ks) words:
        // [nj=2ks: r0r1, r2r3 | nj=2ks+1: r0r1, r2r3]
        U8 pf[2][2];
#pragma unroll
        for (int mi = 0; mi < 2; mi++)
#pragma unroll
            for (int ks = 0; ks < 2; ks++)
#pragma unroll
                for (int hf = 0; hf < 2; hf++) {
                    const int nj = 2 * ks + hf;
                    float p0 = __builtin_amdgcn_exp2f(S[mi][nj][0]);
                    float p1 = __builtin_amdgcn_exp2f(S[mi][nj][1]);
                    float p2 = __builtin_amdgcn_exp2f(S[mi][nj][2]);
                    float p3 = __builtin_amdgcn_exp2f(S[mi][nj][3]);
                    unsigned int m = mw[mi][nj];
                    unsigned int d0 = __builtin_amdgcn_perm(0u, m, 0x01010000u);
                    unsigned int d1 = __builtin_amdgcn_perm(0u, m, 0x03030202u);
                    pf[mi][ks].w[2 * hf]     = pkbf(p0, p1) & d0;
                    pf[mi][ks].w[2 * hf + 1] = pkbf(p2, p3) & d1;
                }

        // O += P @ V ; l += P @ ones (P in registers; V one b128/frag)
        __builtin_amdgcn_s_setprio(1);
#pragma unroll
        for (int ks = 0; ks < 2; ks++) {
            bf16x8 p0 = pf[0][ks].v;
            bf16x8 p1 = pf[1][ks].v;
            lacc[0] = MFMA16(p0, ones, lacc[0]);
            lacc[1] = MFMA16(p1, ones, lacc[1]);
#pragma unroll
            for (int dj = 0; dj < 4; dj++) {
                bf16x8 vf = *(const bf16x8*)&Vs[dj * 16 + ln][vrd[ks]];
                o[0][dj] = MFMA16(p0, vf, o[0][dj]);
                o[1][dj] = MFMA16(p1, vf, o[1][dj]);
            }
        }
        __builtin_amdgcn_s_setprio(0);
    }

#pragma unroll
    for (int mi = 0; mi < 2; mi++) {
        float l0 = 1.0f / lacc[mi][0];
        float l1 = 1.0f / lacc[mi][1];
        float l2 = 1.0f / lacc[mi][2];
        float l3 = 1.0f / lacc[mi][3];
#pragma unroll
        for (int dj = 0; dj < 4; dj++) {
            unsigned short* op = Ob + (size_t)(b * SEQ + q0 + mi * 16 + lg * 4) * EMBED
                                    + h * HDIM + dj * 16 + ln;
            op[0]         = f2bf(o[mi][dj][0] * l0);
            op[EMBED]     = f2bf(o[mi][dj][1] * l1);
            op[2 * EMBED] = f2bf(o[mi][dj][2] * l2);
            op[3 * EMBED] = f2bf(o[mi][dj][3] * l3);
        }
    }
}

extern "C" void kernel_launch(void* const* d_in, const int* in_sizes, int n_in,
                              void* d_out, int out_size, void* d_ws, size_t ws_size,
                              hipStream_t stream)
{
    const float* x  = (const float*)d_in[0];
    const int* mask = (const int*)d_in[1];
    const float* Wq = (const float*)d_in[2];
    const float* bq = (const float*)d_in[3];
    const float* Wk = (const float*)d_in[4];
    const float* bk = (const float*)d_in[5];
    const float* Wv = (const float*)d_in[6];
    const float* bv = (const float*)d_in[7];
    const float* Wo = (const float*)d_in[8];
    const float* bo = (const float*)d_in[9];
    float* outp = (float*)d_out;

    // Workspace layout (88 MB):
    //   [0,8)   Wt: 4x bf16 1024x1024 (transposed weights)
    //   [8,24)  mask8 (0xFF/0x00)
    //   [24,40) Xb (bf16 x) -- aliased by Ob after qkv consumes Xb
    //   [40,56) Qb  [56,72) Kb  [72,88) Vt (V written pre-transposed by qkv)
    char* ws = (char*)d_ws;
    unsigned short* Wt = (unsigned short*)(ws);
    unsigned char*  m8 = (unsigned char*)(ws + ((size_t)8 << 20));
    unsigned short* Xb = (unsigned short*)(ws + ((size_t)24 << 20));
    unsigned short* Ob = Xb;
    unsigned short* Qb = (unsigned short*)(ws + ((size_t)40 << 20));
    unsigned short* Kb = (unsigned short*)(ws + ((size_t)56 << 20));
    unsigned short* Vt = (unsigned short*)(ws + ((size_t)72 << 20));

    prep_kernel<<<XBLK + MBLK + WBLK, 256, 0, stream>>>(
        x, mask, Wq, Wk, Wv, Wo, Xb, m8, Wt);
    qkv_gemm_kernel<<<1536, 256, 0, stream>>>(
        Xb, Wt, bq, bk, bv, Qb, Kb, Vt);
    attn_mfma_kernel<<<1024, 256, 0, stream>>>(
        Qb, Kb, Vt, m8, Ob);
    out_gemm_kernel<<<512, 256, 0, stream>>>(
        Ob, Wt + (size_t)3 * EMBED * EMBED, bo, outp);
}

// Round 14
// 393.144 us; speedup vs baseline: 1.0285x; 1.0285x over previous
//
#include <hip/hip_runtime.h>
#include <hip/hip_bf16.h>

#define EMBED 1024
#define HEADS 16
#define HDIM 64
#define BATCH 4
#define SEQ 2048
#define ROWS (BATCH * SEQ) /* 8192 */
#define LOG2E 1.4426950408889634f

typedef __attribute__((ext_vector_type(8))) short bf16x8;  // 8 bf16 = 4 VGPRs
typedef __attribute__((ext_vector_type(4))) float f32x4;   // MFMA 16x16 acc

#define MFMA16(a, b, c) __builtin_amdgcn_mfma_f32_16x16x32_bf16(a, b, c, 0, 0, 0)

__device__ __forceinline__ unsigned short f2bf(float f) {
    union { float f; unsigned int u; } x; x.f = f;
    unsigned int r = x.u + 0x7fffu + ((x.u >> 16) & 1u); // RNE
    return (unsigned short)(r >> 16);
}

// packed (a,b) -> 2x bf16 in one dword; HW v_cvt_pk_bf16_f32 when available
__device__ __forceinline__ unsigned int pkbf(float a, float b) {
#if __has_builtin(__builtin_amdgcn_cvt_pk_bf16_f32)
    auto v = __builtin_amdgcn_cvt_pk_bf16_f32(a, b);
    unsigned int u; __builtin_memcpy(&u, &v, 4); return u;
#else
    union { __hip_bfloat162 h; unsigned int u; } c;
    c.h = __float22bfloat162_rn(make_float2(a, b)); return c.u;
#endif
}

// async global->LDS, 16 B per lane; lds dest = wave-uniform base + lane*16
__device__ __forceinline__ void gl2lds(const unsigned short* g, unsigned short* l) {
    __builtin_amdgcn_global_load_lds(
        (const __attribute__((address_space(1))) unsigned int*)g,
        (__attribute__((address_space(3))) unsigned int*)l, 16, 0, 0);
}

// ---------------------------------------------------------------------------
// Fused prep: [0,8192) cvt_x | [8192,24576) cvt_mask | [24576,28672) wtrans
// ---------------------------------------------------------------------------
#define XBLK 8192
#define MBLK 16384
#define WBLK 4096

__global__ __launch_bounds__(256) void prep_kernel(
    const float* __restrict__ x, const int* __restrict__ mask,
    const float* __restrict__ W0, const float* __restrict__ W1,
    const float* __restrict__ W2, const float* __restrict__ W3,
    unsigned short* __restrict__ Xb, unsigned char* __restrict__ m8,
    unsigned short* __restrict__ Wt)
{
    __shared__ float t[32][33];
    const int bid = blockIdx.x;
    if (bid < XBLK) {
        int i = (bid * 256 + threadIdx.x) * 4;
        float4 v = *(const float4*)(x + i);
        uint2 o; o.x = pkbf(v.x, v.y); o.y = pkbf(v.z, v.w);
        *(uint2*)(Xb + i) = o;
    } else if (bid < XBLK + MBLK) {
        int i = ((bid - XBLK) * 256 + threadIdx.x) * 4;
        int4 v = *(const int4*)(mask + i);
        uchar4 o;
        o.x = v.x ? 0xFF : 0; o.y = v.y ? 0xFF : 0;
        o.z = v.z ? 0xFF : 0; o.w = v.w ? 0xFF : 0;
        *(uchar4*)(m8 + i) = o;
    } else {
        int f = bid - XBLK - MBLK;           // 0..4095
        int z = f >> 10, rem = f & 1023;
        const float* W = (z == 0) ? W0 : (z == 1) ? W1 : (z == 2) ? W2 : W3;
        unsigned short* o = Wt + (size_t)z * EMBED * EMBED;
        int tx = threadIdx.x & 31, ty = threadIdx.x >> 5;
        int bx = (rem & 31) * 32, by = (rem >> 5) * 32;  // bx: n, by: k
#pragma unroll
        for (int r = 0; r < 32; r += 8)
            t[ty + r][tx] = W[(size_t)(by + ty + r) * EMBED + bx + tx];
        __syncthreads();
#pragma unroll
        for (int r = 0; r < 32; r += 8)
            o[(size_t)(bx + ty + r) * EMBED + by + tx] = f2bf(t[tx][ty + r]);
    }
}

// ---------------------------------------------------------------------------
// bf16 MFMA GEMM: EXACT R8 single-buffered body (best measured config).
// 128x128 tile, BK=64, unpadded XOR-swizzled LDS; gl2lds with per-lane
// swizzled SOURCE addresses. 4 waves, 4x4 16x16x32. m0/n0 = XCD swizzle.
// R12 note: explicit dbuf regressed (dynamic index defeats alias analysis;
// 64 KB LDS halves occupancy). vmode=1: V written transposed to Vt.
// ---------------------------------------------------------------------------
__device__ __forceinline__ void gemm_bf16_body(
    const unsigned short* __restrict__ A, const unsigned short* __restrict__ Bt,
    const float* __restrict__ bias,
    float* __restrict__ outF, unsigned short* __restrict__ outB, float scale,
    int vmode, int m0, int n0)
{
    __shared__ unsigned short As[128][64]; // 16 KB
    __shared__ unsigned short Bs[128][64]; // 16 KB
    const int tid = threadIdx.x;
    const int lane = tid & 63, wid = tid >> 6;
    const int ln = lane & 15, lg = lane >> 4;
    const int wy = wid >> 1, wx = wid & 1;
    const int r0 = wid * 32 + (lane >> 3);
    const int scol = (((lane & 7) ^ ((lane >> 3) & 7)) << 3);
    const unsigned short* Ap = A + (size_t)(m0 + r0) * EMBED + scol;
    const unsigned short* Bp = Bt + (size_t)(n0 + r0) * EMBED + scol;
    unsigned short* lA = &As[wid * 32][0]; // wave-uniform
    unsigned short* lB = &Bs[wid * 32][0];

    f32x4 acc[4][4];
#pragma unroll
    for (int i = 0; i < 4; i++)
#pragma unroll
        for (int j = 0; j < 4; j++) acc[i][j] = (f32x4){0.f, 0.f, 0.f, 0.f};

    for (int k0 = 0; k0 < EMBED; k0 += 64) {
        __syncthreads();
#pragma unroll
        for (int is = 0; is < 4; is++) {
            gl2lds(Ap + k0 + (size_t)(is * 8) * EMBED, lA + is * 8 * 64);
            gl2lds(Bp + k0 + (size_t)(is * 8) * EMBED, lB + is * 8 * 64);
        }
        __syncthreads();
        bf16x8 af[2][4], bfr[2][4];
#pragma unroll
        for (int s = 0; s < 2; s++) {
#pragma unroll
            for (int mi = 0; mi < 4; mi++)
                af[s][mi] = *(const bf16x8*)
                    &As[wy * 64 + mi * 16 + ln][(((lg + 4 * s) ^ (ln & 7)) << 3)];
#pragma unroll
            for (int nj = 0; nj < 4; nj++)
                bfr[s][nj] = *(const bf16x8*)
                    &Bs[wx * 64 + nj * 16 + ln][(((lg + 4 * s) ^ (ln & 7)) << 3)];
        }
#pragma unroll
        for (int s = 0; s < 2; s++)
#pragma unroll
            for (int mi = 0; mi < 4; mi++)
#pragma unroll
                for (int nj = 0; nj < 4; nj++)
                    acc[mi][nj] = MFMA16(af[s][mi], bfr[s][nj], acc[mi][nj]);
    }

#pragma unroll
    for (int mi = 0; mi < 4; mi++) {
#pragma unroll
        for (int nj = 0; nj < 4; nj++) {
            int row = m0 + wy * 64 + mi * 16 + lg * 4;
            int col = n0 + wx * 64 + nj * 16 + ln;
            float bv = bias[col];
            if (vmode) {
                int bb = row >> 11, s = row & (SEQ - 1);
                int hh = col >> 6, dd = col & 63;
                unsigned short* dst = outB +
                    ((size_t)((bb * HEADS + hh) * HDIM + dd)) * SEQ + s;
                uint2 pw;
                pw.x = pkbf(acc[mi][nj][0] + bv, acc[mi][nj][1] + bv);
                pw.y = pkbf(acc[mi][nj][2] + bv, acc[mi][nj][3] + bv);
                *(uint2*)dst = pw;
            } else {
#pragma unroll
                for (int r = 0; r < 4; r++) {
                    float v = (acc[mi][nj][r] + bv) * scale;
                    if (outF) outF[(size_t)(row + r) * EMBED + col] = v;
                    else      outB[(size_t)(row + r) * EMBED + col] = f2bf(v);
                }
            }
        }
    }
}

// qkv: 1-D grid of 1536 with XCD-aware decode (R6).
__global__ __launch_bounds__(256) void qkv_gemm_kernel(
    const unsigned short* __restrict__ Xb, const unsigned short* __restrict__ Wt,
    const float* __restrict__ bq, const float* __restrict__ bk,
    const float* __restrict__ bv,
    unsigned short* __restrict__ Qb, unsigned short* __restrict__ Kb,
    unsigned short* __restrict__ Vt)
{
    const int bid = blockIdx.x;
    const int xcd = bid & 7;
    const int idx = bid >> 3;        // 0..191
    const int bx  = idx & 7;         // N-block 0..7
    const int yi  = (idx >> 3) & 7;  // 0..7
    const int z   = idx >> 6;        // 0..2
    const int by  = xcd * 8 + yi;    // M-block 0..63

    const unsigned short* Bt = Wt + (size_t)z * EMBED * EMBED;
    const float* bias = (z == 0) ? bq : (z == 1) ? bk : bv;
    unsigned short* out = (z == 0) ? Qb : (z == 1) ? Kb : Vt;
    float scale = (z == 0) ? 0.125f * LOG2E : 1.0f;
    gemm_bf16_body(Xb, Bt, bias, nullptr, out, scale, z == 2,
                   by * 128, bx * 128);
}

// out: 1-D grid of 512, same XCD decode.
__global__ __launch_bounds__(256) void out_gemm_kernel(
    const unsigned short* __restrict__ Ob, const unsigned short* __restrict__ Wto,
    const float* __restrict__ bo, float* __restrict__ out)
{
    const int bid = blockIdx.x;
    const int xcd = bid & 7;
    const int idx = bid >> 3;        // 0..63
    const int bx  = idx & 7;
    const int yi  = idx >> 3;        // 0..7
    const int by  = xcd * 8 + yi;    // 0..63
    gemm_bf16_body(Ob, Wto, bo, out, nullptr, 1.0f, 0, by * 128, bx * 128);
}

// ---------------------------------------------------------------------------
// Flash attention, bf16 MFMA, no-max softmax. R8 dataflow (in-register P via
// sigma-permutation, sigma-permuted V in LDS, XCD decode -- HW-verified),
// restructured as STATIC-NAME DOUBLE-BUFFER (R14). Per 64-row tile t:
//   { issue K-DMA(t+1)->KN + V/mask reg-loads(t+1) | compute tile t
//     (~36 MFMA + exp2, ~800 cyc) | land V(t+1) ds_writes->VN | ONE barrier }
// Every wait sits a full compute phase after its issue; barriers 64 -> 32.
// Fixes each prior failure's flaw: static buffer NAMES Ks0/Ks1/Vs0/Vs1
// (R12's runtime index defeated alias analysis), KVBLK=64 + R8 swizzles
// (R3's KVBLK=32 had 18.9M conflicts), unconditional wrap-prefetch -- no
// guards (R2's guarded loads got sunk). LDS 32 KB -> 4 blocks/CU kept.
// R13 note: s_setprio perturbed codegen (VGPR 96->76, +26% time): reverted.
// ---------------------------------------------------------------------------
__global__ __launch_bounds__(256) void attn_mfma_kernel(
    const unsigned short* __restrict__ Qb, const unsigned short* __restrict__ Kb,
    const unsigned short* __restrict__ Vt, const unsigned char* __restrict__ mask8,
    unsigned short* __restrict__ Ob)
{
    __shared__ unsigned short Ks0[64][64], Ks1[64][64]; // 16 KB (swizzled)
    __shared__ unsigned short Vs0[64][64], Vs1[64][64]; // 16 KB (sigma+swz)
    const int tid = threadIdx.x;
    const int lane = tid & 63, wid = tid >> 6;
    const int ln = lane & 15, lg = lane >> 4;

    // XCD decode: xcd owns bh in [xcd*8, xcd*8+8), all 16 q-blocks each
    const int bid = blockIdx.x;
    const int xcd = bid & 7;
    const int i5 = bid >> 3;         // 0..127
    const int qx = i5 & 15;          // q-block 0..15
    const int bh = xcd * 8 + (i5 >> 4);
    const int h = bh & 15, b = bh >> 4;
    const int q0 = qx * 128 + wid * 32;

    bf16x8 qf[2][2]; // B-frag: row q0+mi*16+ln, d = ks*32+lg*8..
#pragma unroll
    for (int mi = 0; mi < 2; mi++)
#pragma unroll
        for (int ks = 0; ks < 2; ks++)
            qf[mi][ks] = *(const bf16x8*)(Qb +
                (size_t)(b * SEQ + q0 + mi * 16 + ln) * EMBED + h * HDIM + ks * 32 + lg * 8);

    bf16x8 ones;
#pragma unroll
    for (int i = 0; i < 8; i++) ones[i] = (short)0x3F80; // bf16 1.0

    f32x4 o[2][4];
#pragma unroll
    for (int mi = 0; mi < 2; mi++)
#pragma unroll
        for (int dj = 0; dj < 4; dj++) o[mi][dj] = (f32x4){0.f, 0.f, 0.f, 0.f};
    f32x4 lacc[2] = {(f32x4){0.f, 0.f, 0.f, 0.f}, (f32x4){0.f, 0.f, 0.f, 0.f}};

    // K staging (gl2lds): srow = tid>>3, source chunk = (tid&7)^(srow&7)
    const int srow = tid >> 3;
    const int scolK = (((tid & 7) ^ ((tid >> 3) & 7)) << 3);
    const unsigned short* Kp = Kb + (size_t)(b * SEQ + srow) * EMBED + h * HDIM + scolK;
    const int lKo = (srow & ~7) * 64;   // wave-uniform base offset (shorts)

    // V reg-staging (sigma-permuted): thread (vrow = tid>>2, vu = tid&3)
    // writes dest chunks c = vu and vu+4 of row vrow; loads kseq 4vu +
    // {0,16,32,48}. Phys chunk = c ^ (vrow&7).
    const int vrow = tid >> 2, vu = tid & 3;
    const unsigned short* Vp = Vt + (size_t)((b * HEADS + h) * HDIM + vrow) * SEQ + 4 * vu;
    const int vVo = vrow * 64;          // row base offset (shorts)
    const int vw0 = ((vu ^ (vrow & 7)) << 3);
    const int vw1 = (((vu + 4) ^ (vrow & 7)) << 3);

    const unsigned char* mq0 = mask8 + (size_t)b * SEQ * SEQ + (size_t)(q0 + ln) * SEQ;
    const unsigned char* mq1 = mq0 + (size_t)16 * SEQ;

    // swizzled fragment-read columns
    const int swk = ((lg ^ (ln & 7)) << 3);            // Ks (QK^T)
    int vrd[2];                                         // Vs (PV), per ks
#pragma unroll
    for (int ks = 0; ks < 2; ks++)
        vrd[ks] = ((4 * ks + lg) ^ (ln & 7)) << 3;

    union U8 { bf16x8 v; unsigned int w[4]; };
    unsigned int mwA[2][4], mwB[2][4];

    // ---- prologue: stage tile 0 into buf0, mask(0) -> mwA ----
    gl2lds(Kp, &Ks0[0][0] + lKo);
    gl2lds(Kp + (size_t)32 * EMBED, &Ks0[0][0] + lKo + 32 * 64);
    {
        uint2 v0 = *(const uint2*)(Vp);
        uint2 v1 = *(const uint2*)(Vp + 16);
        uint2 v2 = *(const uint2*)(Vp + 32);
        uint2 v3 = *(const uint2*)(Vp + 48);
        uint4 w0; w0.x = v0.x; w0.y = v0.y; w0.z = v1.x; w0.w = v1.y;
        uint4 w1; w1.x = v2.x; w1.y = v2.y; w1.z = v3.x; w1.w = v3.y;
        *(uint4*)(&Vs0[0][0] + vVo + vw0) = w0;
        *(uint4*)(&Vs0[0][0] + vVo + vw1) = w1;
    }
#pragma unroll
    for (int mi = 0; mi < 2; mi++) {
        const unsigned char* mq = mi ? mq1 : mq0;
#pragma unroll
        for (int nj = 0; nj < 4; nj++)
            mwA[mi][nj] = *(const unsigned int*)(mq + nj * 16 + lg * 4);
    }
    __syncthreads(); // tile 0 staged (DMA drained + V writes visible)

    // One iteration: stage tile NXT into (KN,VN) around compute on (KC,VC)
    // with mask regs MWC; next-tile mask -> MWN. ONE barrier at the end.
#define ATTN_ITER(KC, VC, KN, VN, MWC, MWN, NXT)                              \
    {                                                                          \
        const int nxt_ = (NXT);                                                \
        gl2lds(Kp + (size_t)nxt_ * EMBED, &KN[0][0] + lKo);                    \
        gl2lds(Kp + (size_t)(nxt_ + 32) * EMBED, &KN[0][0] + lKo + 32 * 64);   \
        uint2 v0 = *(const uint2*)(Vp + nxt_);                                 \
        uint2 v1 = *(const uint2*)(Vp + nxt_ + 16);                            \
        uint2 v2 = *(const uint2*)(Vp + nxt_ + 32);                            \
        uint2 v3 = *(const uint2*)(Vp + nxt_ + 48);                            \
        _Pragma("unroll")                                                      \
        for (int mi = 0; mi < 2; mi++) {                                       \
            const unsigned char* mq = (mi ? mq1 : mq0) + nxt_;                 \
            _Pragma("unroll")                                                  \
            for (int nj = 0; nj < 4; nj++)                                     \
                MWN[mi][nj] = *(const unsigned int*)(mq + nj * 16 + lg * 4);   \
        }                                                                      \
        __builtin_amdgcn_sched_barrier(0); /* pin: loads issued before compute */ \
        f32x4 S[2][4];                                                         \
        _Pragma("unroll")                                                      \
        for (int nj = 0; nj < 4; nj++) {                                       \
            bf16x8 k0 = *(const bf16x8*)&KC[nj * 16 + ln][swk];                \
            bf16x8 k1 = *(const bf16x8*)&KC[nj * 16 + ln][swk ^ 32];           \
            _Pragma("unroll")                                                  \
            for (int mi = 0; mi < 2; mi++) {                                   \
                f32x4 t2 = (f32x4){0.f, 0.f, 0.f, 0.f};                        \
                t2 = MFMA16(k0, qf[mi][0], t2);                                \
                t2 = MFMA16(k1, qf[mi][1], t2);                                \
                S[mi][nj] = t2;                                                \
            }                                                                  \
        }                                                                      \
        U8 pf[2][2];                                                           \
        _Pragma("unroll")                                                      \
        for (int mi = 0; mi < 2; mi++)                                         \
            _Pragma("unroll")                                                  \
            for (int ks = 0; ks < 2; ks++)                                     \
                _Pragma("unroll")                                              \
                for (int hf = 0; hf < 2; hf++) {                               \
                    const int nj = 2 * ks + hf;                                \
                    float p0 = __builtin_amdgcn_exp2f(S[mi][nj][0]);           \
                    float p1 = __builtin_amdgcn_exp2f(S[mi][nj][1]);           \
                    float p2 = __builtin_amdgcn_exp2f(S[mi][nj][2]);           \
                    float p3 = __builtin_amdgcn_exp2f(S[mi][nj][3]);           \
                    unsigned int m = MWC[mi][nj];                              \
                    unsigned int d0 = __builtin_amdgcn_perm(0u, m, 0x01010000u); \
                    unsigned int d1 = __builtin_amdgcn_perm(0u, m, 0x03030202u); \
                    pf[mi][ks].w[2 * hf]     = pkbf(p0, p1) & d0;              \
                    pf[mi][ks].w[2 * hf + 1] = pkbf(p2, p3) & d1;              \
                }                                                              \
        _Pragma("unroll")                                                      \
        for (int ks = 0; ks < 2; ks++) {                                       \
            bf16x8 p0 = pf[0][ks].v;                                           \
            bf16x8 p1 = pf[1][ks].v;                                           \
            lacc[0] = MFMA16(p0, ones, lacc[0]);                               \
            lacc[1] = MFMA16(p1, ones, lacc[1]);                               \
            _Pragma("unroll")                                                  \
            for (int dj = 0; dj < 4; dj++) {                                   \
                bf16x8 vf = *(const bf16x8*)&VC[dj * 16 + ln][vrd[ks]];        \
                o[0][dj] = MFMA16(p0, vf, o[0][dj]);                           \
                o[1][dj] = MFMA16(p1, vf, o[1][dj]);                           \
            }                                                                  \
        }                                                                      \
        __builtin_amdgcn_sched_barrier(0); /* pin: V-land stays after compute */ \
        uint4 w0; w0.x = v0.x; w0.y = v0.y; w0.z = v1.x; w0.w = v1.y;          \
        uint4 w1; w1.x = v2.x; w1.y = v2.y; w1.z = v3.x; w1.w = v3.y;          \
        *(uint4*)(&VN[0][0] + vVo + vw0) = w0;                                 \
        *(uint4*)(&VN[0][0] + vVo + vw1) = w1;                                 \
        __syncthreads();                                                       \
    }

    for (int kt = 0; kt < SEQ; kt += 128) {
        // sub-iter A: compute tile kt (buf0), stage kt+64 -> buf1
        ATTN_ITER(Ks0, Vs0, Ks1, Vs1, mwA, mwB, kt + 64)
        // sub-iter B: compute tile kt+64 (buf1), stage kt+128 -> buf0
        // (last iter wraps to tile 0: staged but never read -- in-bounds)
        ATTN_ITER(Ks1, Vs1, Ks0, Vs0, mwB, mwA, (kt + 128) & (SEQ - 1))
    }
#undef ATTN_ITER

#pragma unroll
    for (int mi = 0; mi < 2; mi++) {
        float l0 = 1.0f / lacc[mi][0];
        float l1 = 1.0f / lacc[mi][1];
        float l2 = 1.0f / lacc[mi][2];
        float l3 = 1.0f / lacc[mi][3];
#pragma unroll
        for (int dj = 0; dj < 4; dj++) {
            unsigned short* op = Ob + (size_t)(b * SEQ + q0 + mi * 16 + lg * 4) * EMBED
                                    + h * HDIM + dj * 16 + ln;
            op[0]         = f2bf(o[mi][dj][0] * l0);
            op[EMBED]     = f2bf(o[mi][dj][1] * l1);
            op[2 * EMBED] = f2bf(o[mi][dj][2] * l2);
            op[3 * EMBED] = f2bf(o[mi][dj][3] * l3);
        }
    }
}

extern "C" void kernel_launch(void* const* d_in, const int* in_sizes, int n_in,
                              void* d_out, int out_size, void* d_ws, size_t ws_size,
                              hipStream_t stream)
{
    const float* x  = (const float*)d_in[0];
    const int* mask = (const int*)d_in[1];
    const float* Wq = (const float*)d_in[2];
    const float* bq = (const float*)d_in[3];
    const float* Wk = (const float*)d_in[4];
    const float* bk = (const float*)d_in[5];
    const float* Wv = (const float*)d_in[6];
    const float* bv = (const float*)d_in[7];
    const float* Wo = (const float*)d_in[8];
    const float* bo = (const float*)d_in[9];
    float* outp = (float*)d_out;

    // Workspace layout (88 MB):
    //   [0,8)   Wt: 4x bf16 1024x1024 (transposed weights)
    //   [8,24)  mask8 (0xFF/0x00)
    //   [24,40) Xb (bf16 x) -- aliased by Ob after qkv consumes Xb
    //   [40,56) Qb  [56,72) Kb  [72,88) Vt (V written pre-transposed by qkv)
    char* ws = (char*)d_ws;
    unsigned short* Wt = (unsigned short*)(ws);
    unsigned char*  m8 = (unsigned char*)(ws + ((size_t)8 << 20));
    unsigned short* Xb = (unsigned short*)(ws + ((size_t)24 << 20));
    unsigned short* Ob = Xb;
    unsigned short* Qb = (unsigned short*)(ws + ((size_t)40 << 20));
    unsigned short* Kb = (unsigned short*)(ws + ((size_t)56 << 20));
    unsigned short* Vt = (unsigned short*)(ws + ((size_t)72 << 20));

    prep_kernel<<<XBLK + MBLK + WBLK, 256, 0, stream>>>(
        x, mask, Wq, Wk, Wv, Wo, Xb, m8, Wt);
    qkv_gemm_kernel<<<1536, 256, 0, stream>>>(
        Xb, Wt, bq, bk, bv, Qb, Kb, Vt);
    attn_mfma_kernel<<<1024, 256, 0, stream>>>(
        Qb, Kb, Vt, m8, Ob);
    out_gemm_kernel<<<512, 256, 0, stream>>>(
        Ob, Wt + (size_t)3 * EMBED * EMBED, bo, outp);
}

// Round 15
// 380.983 us; speedup vs baseline: 1.0613x; 1.0319x over previous
//
#include <hip/hip_runtime.h>
#include <hip/hip_bf16.h>

#define EMBED 1024
#define HEADS 16
#define HDIM 64
#define BATCH 4
#define SEQ 2048
#define ROWS (BATCH * SEQ) /* 8192 */
#define LOG2E 1.4426950408889634f

typedef __attribute__((ext_vector_type(8))) short bf16x8;  // 8 bf16 = 4 VGPRs
typedef __attribute__((ext_vector_type(4))) float f32x4;   // MFMA 16x16 acc

#define MFMA16(a, b, c) __builtin_amdgcn_mfma_f32_16x16x32_bf16(a, b, c, 0, 0, 0)

__device__ __forceinline__ unsigned short f2bf(float f) {
    union { float f; unsigned int u; } x; x.f = f;
    unsigned int r = x.u + 0x7fffu + ((x.u >> 16) & 1u); // RNE
    return (unsigned short)(r >> 16);
}

// packed (a,b) -> 2x bf16 in one dword; HW v_cvt_pk_bf16_f32 when available
__device__ __forceinline__ unsigned int pkbf(float a, float b) {
#if __has_builtin(__builtin_amdgcn_cvt_pk_bf16_f32)
    auto v = __builtin_amdgcn_cvt_pk_bf16_f32(a, b);
    unsigned int u; __builtin_memcpy(&u, &v, 4); return u;
#else
    union { __hip_bfloat162 h; unsigned int u; } c;
    c.h = __float22bfloat162_rn(make_float2(a, b)); return c.u;
#endif
}

// async global->LDS, 16 B per lane; lds dest = wave-uniform base + lane*16
__device__ __forceinline__ void gl2lds(const unsigned short* g, unsigned short* l) {
    __builtin_amdgcn_global_load_lds(
        (const __attribute__((address_space(1))) unsigned int*)g,
        (__attribute__((address_space(3))) unsigned int*)l, 16, 0, 0);
}

// ---------------------------------------------------------------------------
// Fused prep: [0,8192) cvt_x | [8192,24576) cvt_mask | [24576,28672) wtrans
// ---------------------------------------------------------------------------
#define XBLK 8192
#define MBLK 16384
#define WBLK 4096

__global__ __launch_bounds__(256) void prep_kernel(
    const float* __restrict__ x, const int* __restrict__ mask,
    const float* __restrict__ W0, const float* __restrict__ W1,
    const float* __restrict__ W2, const float* __restrict__ W3,
    unsigned short* __restrict__ Xb, unsigned char* __restrict__ m8,
    unsigned short* __restrict__ Wt)
{
    __shared__ float t[32][33];
    const int bid = blockIdx.x;
    if (bid < XBLK) {
        int i = (bid * 256 + threadIdx.x) * 4;
        float4 v = *(const float4*)(x + i);
        uint2 o; o.x = pkbf(v.x, v.y); o.y = pkbf(v.z, v.w);
        *(uint2*)(Xb + i) = o;
    } else if (bid < XBLK + MBLK) {
        int i = ((bid - XBLK) * 256 + threadIdx.x) * 4;
        int4 v = *(const int4*)(mask + i);
        uchar4 o;
        o.x = v.x ? 0xFF : 0; o.y = v.y ? 0xFF : 0;
        o.z = v.z ? 0xFF : 0; o.w = v.w ? 0xFF : 0;
        *(uchar4*)(m8 + i) = o;
    } else {
        int f = bid - XBLK - MBLK;           // 0..4095
        int z = f >> 10, rem = f & 1023;
        const float* W = (z == 0) ? W0 : (z == 1) ? W1 : (z == 2) ? W2 : W3;
        unsigned short* o = Wt + (size_t)z * EMBED * EMBED;
        int tx = threadIdx.x & 31, ty = threadIdx.x >> 5;
        int bx = (rem & 31) * 32, by = (rem >> 5) * 32;  // bx: n, by: k
#pragma unroll
        for (int r = 0; r < 32; r += 8)
            t[ty + r][tx] = W[(size_t)(by + ty + r) * EMBED + bx + tx];
        __syncthreads();
#pragma unroll
        for (int r = 0; r < 32; r += 8)
            o[(size_t)(bx + ty + r) * EMBED + by + tx] = f2bf(t[tx][ty + r]);
    }
}

// ---------------------------------------------------------------------------
// bf16 MFMA GEMM: 128x128 tile, BK=64, unpadded XOR-swizzled LDS (128-B rows,
// phys_chunk = logical ^ (row&7)); staged via gl2lds with per-lane swizzled
// SOURCE addresses. 4 waves, 4x4 16x16x32. m0/n0 passed in (XCD swizzle).
// Single-buffered: R12 (dynamic-index dbuf) and R14-class pipelining both
// regressed; implicit cross-block overlap at 5 blocks/CU is the optimum.
// vmode=1: V projection writes output transposed to Vt[b][h][d][kseq].
// ---------------------------------------------------------------------------
__device__ __forceinline__ void gemm_bf16_body(
    const unsigned short* __restrict__ A, const unsigned short* __restrict__ Bt,
    const float* __restrict__ bias,
    float* __restrict__ outF, unsigned short* __restrict__ outB, float scale,
    int vmode, int m0, int n0)
{
    __shared__ unsigned short As[128][64]; // 16 KB
    __shared__ unsigned short Bs[128][64]; // 16 KB
    const int tid = threadIdx.x;
    const int lane = tid & 63, wid = tid >> 6;
    const int ln = lane & 15, lg = lane >> 4;
    const int wy = wid >> 1, wx = wid & 1;
    // staging: lane stages row r0(+8*is), phys chunk = lane&7,
    // swizzled source logical chunk = (lane&7) ^ (r&7), r&7 = lane>>3
    const int r0 = wid * 32 + (lane >> 3);
    const int scol = (((lane & 7) ^ ((lane >> 3) & 7)) << 3);
    const unsigned short* Ap = A + (size_t)(m0 + r0) * EMBED + scol;
    const unsigned short* Bp = Bt + (size_t)(n0 + r0) * EMBED + scol;
    unsigned short* lA = &As[wid * 32][0]; // wave-uniform
    unsigned short* lB = &Bs[wid * 32][0];

    f32x4 acc[4][4];
#pragma unroll
    for (int i = 0; i < 4; i++)
#pragma unroll
        for (int j = 0; j < 4; j++) acc[i][j] = (f32x4){0.f, 0.f, 0.f, 0.f};

    for (int k0 = 0; k0 < EMBED; k0 += 64) {
        __syncthreads();
#pragma unroll
        for (int is = 0; is < 4; is++) {
            gl2lds(Ap + k0 + (size_t)(is * 8) * EMBED, lA + is * 8 * 64);
            gl2lds(Bp + k0 + (size_t)(is * 8) * EMBED, lB + is * 8 * 64);
        }
        __syncthreads();
        bf16x8 af[2][4], bfr[2][4];
#pragma unroll
        for (int s = 0; s < 2; s++) {
#pragma unroll
            for (int mi = 0; mi < 4; mi++)
                af[s][mi] = *(const bf16x8*)
                    &As[wy * 64 + mi * 16 + ln][(((lg + 4 * s) ^ (ln & 7)) << 3)];
#pragma unroll
            for (int nj = 0; nj < 4; nj++)
                bfr[s][nj] = *(const bf16x8*)
                    &Bs[wx * 64 + nj * 16 + ln][(((lg + 4 * s) ^ (ln & 7)) << 3)];
        }
#pragma unroll
        for (int s = 0; s < 2; s++)
#pragma unroll
            for (int mi = 0; mi < 4; mi++)
#pragma unroll
                for (int nj = 0; nj < 4; nj++)
                    acc[mi][nj] = MFMA16(af[s][mi], bfr[s][nj], acc[mi][nj]);
    }

#pragma unroll
    for (int mi = 0; mi < 4; mi++) {
#pragma unroll
        for (int nj = 0; nj < 4; nj++) {
            int row = m0 + wy * 64 + mi * 16 + lg * 4;
            int col = n0 + wx * 64 + nj * 16 + ln;
            float bv = bias[col];
            if (vmode) {
                // V output: Vt[(b*HEADS+h)*HDIM + d][s], 4 consecutive s/lane
                int bb = row >> 11, s = row & (SEQ - 1);
                int hh = col >> 6, dd = col & 63;
                unsigned short* dst = outB +
                    ((size_t)((bb * HEADS + hh) * HDIM + dd)) * SEQ + s;
                uint2 pw;
                pw.x = pkbf(acc[mi][nj][0] + bv, acc[mi][nj][1] + bv);
                pw.y = pkbf(acc[mi][nj][2] + bv, acc[mi][nj][3] + bv);
                *(uint2*)dst = pw;
            } else {
#pragma unroll
                for (int r = 0; r < 4; r++) {
                    float v = (acc[mi][nj][r] + bv) * scale;
                    if (outF) outF[(size_t)(row + r) * EMBED + col] = v;
                    else      outB[(size_t)(row + r) * EMBED + col] = f2bf(v);
                }
            }
        }
    }
}

// qkv: 1-D grid of 1536 with XCD-aware decode (R6: each XCD gets a
// contiguous 8-strip m-chunk; A working set 2 MB fits its 4 MB L2).
__global__ __launch_bounds__(256) void qkv_gemm_kernel(
    const unsigned short* __restrict__ Xb, const unsigned short* __restrict__ Wt,
    const float* __restrict__ bq, const float* __restrict__ bk,
    const float* __restrict__ bv,
    unsigned short* __restrict__ Qb, unsigned short* __restrict__ Kb,
    unsigned short* __restrict__ Vt)
{
    const int bid = blockIdx.x;
    const int xcd = bid & 7;
    const int idx = bid >> 3;        // 0..191
    const int bx  = idx & 7;         // N-block 0..7
    const int yi  = (idx >> 3) & 7;  // 0..7
    const int z   = idx >> 6;        // 0..2
    const int by  = xcd * 8 + yi;    // M-block 0..63

    const unsigned short* Bt = Wt + (size_t)z * EMBED * EMBED;
    const float* bias = (z == 0) ? bq : (z == 1) ? bk : bv;
    unsigned short* out = (z == 0) ? Qb : (z == 1) ? Kb : Vt;
    // fold 1/sqrt(HDIM) AND log2(e) into Q so softmax uses raw v_exp_f32
    float scale = (z == 0) ? 0.125f * LOG2E : 1.0f;
    gemm_bf16_body(Xb, Bt, bias, nullptr, out, scale, z == 2,
                   by * 128, bx * 128);
}

// out: 1-D grid of 512, same XCD decode (8*8*8=512 bijective).
__global__ __launch_bounds__(256) void out_gemm_kernel(
    const unsigned short* __restrict__ Ob, const unsigned short* __restrict__ Wto,
    const float* __restrict__ bo, float* __restrict__ out)
{
    const int bid = blockIdx.x;
    const int xcd = bid & 7;
    const int idx = bid >> 3;        // 0..63
    const int bx  = idx & 7;
    const int yi  = idx >> 3;        // 0..7
    const int by  = xcd * 8 + yi;    // 0..63
    gemm_bf16_body(Ob, Wto, bo, out, nullptr, 1.0f, 0, by * 128, bx * 128);
}

// ---------------------------------------------------------------------------
// Flash attention, bf16 MFMA, no-max softmax. EXACT R8 kernel (best measured:
// 159.6 us) -- in-register P via sigma-permutation, sigma-permuted V in LDS,
// XCD-aware (b,h) decode. FROZEN: R2 (reg prefetch, neutral), R3 (KVBLK=32
// dbuf, -28%), R9 (KVBLK=128, -3%), R10 (split-q, -65%), R13 (setprio, -26%),
// R14 (static-name dbuf, -9%) all refuted restructuring. The implicit
// cross-block overlap of the 2-barrier structure at 4 blocks/CU is the
// source-level optimum; the path beyond is producer-consumer wave
// specialization / inline-asm K-loop (AITER-class), not incremental edits.
// ---------------------------------------------------------------------------
__global__ __launch_bounds__(256) void attn_mfma_kernel(
    const unsigned short* __restrict__ Qb, const unsigned short* __restrict__ Kb,
    const unsigned short* __restrict__ Vt, const unsigned char* __restrict__ mask8,
    unsigned short* __restrict__ Ob)
{
    __shared__ unsigned short Ks[64][64];    // [kseq][d]     8 KB (swizzled)
    __shared__ unsigned short Vs[64][64];    // [d][sigma(k)]  8 KB (swizzled)
    const int tid = threadIdx.x;
    const int lane = tid & 63, wid = tid >> 6;
    const int ln = lane & 15, lg = lane >> 4;

    // XCD decode: xcd owns bh in [xcd*8, xcd*8+8), all 16 q-blocks each
    const int bid = blockIdx.x;
    const int xcd = bid & 7;
    const int i5 = bid >> 3;         // 0..127
    const int qx = i5 & 15;          // q-block 0..15
    const int bh = xcd * 8 + (i5 >> 4);
    const int h = bh & 15, b = bh >> 4;
    const int q0 = qx * 128 + wid * 32;

    bf16x8 qf[2][2]; // B-frag: row q0+mi*16+ln, d = ks*32+lg*8..
#pragma unroll
    for (int mi = 0; mi < 2; mi++)
#pragma unroll
        for (int ks = 0; ks < 2; ks++)
            qf[mi][ks] = *(const bf16x8*)(Qb +
                (size_t)(b * SEQ + q0 + mi * 16 + ln) * EMBED + h * HDIM + ks * 32 + lg * 8);

    bf16x8 ones;
#pragma unroll
    for (int i = 0; i < 8; i++) ones[i] = (short)0x3F80; // bf16 1.0

    f32x4 o[2][4];
#pragma unroll
    for (int mi = 0; mi < 2; mi++)
#pragma unroll
        for (int dj = 0; dj < 4; dj++) o[mi][dj] = (f32x4){0.f, 0.f, 0.f, 0.f};
    f32x4 lacc[2] = {(f32x4){0.f, 0.f, 0.f, 0.f}, (f32x4){0.f, 0.f, 0.f, 0.f}};

    // K staging (gl2lds): srow = tid>>3, source chunk = (tid&7)^(srow&7)
    const int srow = tid >> 3;
    const int scolK = (((tid & 7) ^ ((tid >> 3) & 7)) << 3);
    const unsigned short* Kp = Kb + (size_t)(b * SEQ + srow) * EMBED + h * HDIM + scolK;
    unsigned short* lK = &Ks[srow & ~7][0]; // wave-uniform

    // V reg-staging (sigma-permuted): thread (vrow = tid>>2, vu = tid&3)
    // writes dest chunks c = vu and vu+4 of row vrow. Chunk c holds tile
    // positions 8c..8c+7 = values V[row][32(c>>2) + 4(c&3) + (j&3) + 16(j>>2)]
    // -> two 8-B granules at kseq 4(c&3)+32(c>>2) and +16. Loads for both
    // chunks: kt + 4*vu + {0,16,32,48} shorts. Phys chunk = c ^ (vrow&7).
    const int vrow = tid >> 2, vu = tid & 3;
    const unsigned short* Vp = Vt + (size_t)((b * HEADS + h) * HDIM + vrow) * SEQ + 4 * vu;
    unsigned short* vdst = &Vs[vrow][0];
    const int vw0 = ((vu ^ (vrow & 7)) << 3);
    const int vw1 = (((vu + 4) ^ (vrow & 7)) << 3);

    const unsigned char* mq0 = mask8 + (size_t)b * SEQ * SEQ + (size_t)(q0 + ln) * SEQ;
    const unsigned char* mq1 = mq0 + (size_t)16 * SEQ;

    // swizzled fragment-read columns
    const int swk = ((lg ^ (ln & 7)) << 3);            // Ks (QK^T)
    int vrd[2];                                         // Vs (PV), per ks
#pragma unroll
    for (int ks = 0; ks < 2; ks++)
        vrd[ks] = ((4 * ks + lg) ^ (ln & 7)) << 3;

    union U8 { bf16x8 v; unsigned int w[4]; };

    for (int kt = 0; kt < SEQ; kt += 64) {
        // mask loads: independent of LDS, overlap barrier waits
        unsigned int mw[2][4];
#pragma unroll
        for (int mi = 0; mi < 2; mi++) {
            const unsigned char* mq = (mi ? mq1 : mq0) + kt;
#pragma unroll
            for (int nj = 0; nj < 4; nj++)
                mw[mi][nj] = *(const unsigned int*)(mq + nj * 16 + lg * 4);
        }

        // V tile loads to regs (read-only global; no barrier hazard)
        uint2 v0 = *(const uint2*)(Vp + kt);
        uint2 v1 = *(const uint2*)(Vp + kt + 16);
        uint2 v2 = *(const uint2*)(Vp + kt + 32);
        uint2 v3 = *(const uint2*)(Vp + kt + 48);

        __syncthreads(); // previous tile fully consumed
        gl2lds(Kp + (size_t)kt * EMBED, lK);
        gl2lds(Kp + (size_t)(kt + 32) * EMBED, lK + 32 * 64);
        {
            uint4 w0; w0.x = v0.x; w0.y = v0.y; w0.z = v1.x; w0.w = v1.y;
            uint4 w1; w1.x = v2.x; w1.y = v2.y; w1.z = v3.x; w1.w = v3.y;
            *(uint4*)(vdst + vw0) = w0;
            *(uint4*)(vdst + vw1) = w1;
        }
        __syncthreads(); // DMA + V writes drained

        // S^T: rows = kseq (nj*16+lg*4+reg), cols = q (mi*16+ln)
        f32x4 S[2][4];
#pragma unroll
        for (int nj = 0; nj < 4; nj++) {
            bf16x8 k0 = *(const bf16x8*)&Ks[nj * 16 + ln][swk];
            bf16x8 k1 = *(const bf16x8*)&Ks[nj * 16 + ln][swk ^ 32];
#pragma unroll
            for (int mi = 0; mi < 2; mi++) {
                f32x4 t2 = (f32x4){0.f, 0.f, 0.f, 0.f};
                t2 = MFMA16(k0, qf[mi][0], t2);
                t2 = MFMA16(k1, qf[mi][1], t2);
                S[mi][nj] = t2;
            }
        }

        // exp2 + packed cvt + mask-AND, assembled directly into PV A-frags
        // (sigma order; HW-verified). Frag (mi,ks) words:
        // [nj=2ks: r0r1, r2r3 | nj=2ks+1: r0r1, r2r3]
        U8 pf[2][2];
#pragma unroll
        for (int mi = 0; mi < 2; mi++)
#pragma unroll
            for (int ks = 0; ks < 2; ks++)
#pragma unroll
                for (int hf = 0; hf < 2; hf++) {
                    const int nj = 2 * ks + hf;
                    float p0 = __builtin_amdgcn_exp2f(S[mi][nj][0]);
                    float p1 = __builtin_amdgcn_exp2f(S[mi][nj][1]);
                    float p2 = __builtin_amdgcn_exp2f(S[mi][nj][2]);
                    float p3 = __builtin_amdgcn_exp2f(S[mi][nj][3]);
                    unsigned int m = mw[mi][nj];
                    unsigned int d0 = __builtin_amdgcn_perm(0u, m, 0x01010000u);
                    unsigned int d1 = __builtin_amdgcn_perm(0u, m, 0x03030202u);
                    pf[mi][ks].w[2 * hf]     = pkbf(p0, p1) & d0;
                    pf[mi][ks].w[2 * hf + 1] = pkbf(p2, p3) & d1;
                }

        // O += P @ V ; l += P @ ones (P in registers; V one b128/frag)
#pragma unroll
        for (int ks = 0; ks < 2; ks++) {
            bf16x8 p0 = pf[0][ks].v;
            bf16x8 p1 = pf[1][ks].v;
            lacc[0] = MFMA16(p0, ones, lacc[0]);
            lacc[1] = MFMA16(p1, ones, lacc[1]);
#pragma unroll
            for (int dj = 0; dj < 4; dj++) {
                bf16x8 vf = *(const bf16x8*)&Vs[dj * 16 + ln][vrd[ks]];
                o[0][dj] = MFMA16(p0, vf, o[0][dj]);
                o[1][dj] = MFMA16(p1, vf, o[1][dj]);
            }
        }
    }

#pragma unroll
    for (int mi = 0; mi < 2; mi++) {
        float l0 = 1.0f / lacc[mi][0];
        float l1 = 1.0f / lacc[mi][1];
        float l2 = 1.0f / lacc[mi][2];
        float l3 = 1.0f / lacc[mi][3];
#pragma unroll
        for (int dj = 0; dj < 4; dj++) {
            unsigned short* op = Ob + (size_t)(b * SEQ + q0 + mi * 16 + lg * 4) * EMBED
                                    + h * HDIM + dj * 16 + ln;
            op[0]         = f2bf(o[mi][dj][0] * l0);
            op[EMBED]     = f2bf(o[mi][dj][1] * l1);
            op[2 * EMBED] = f2bf(o[mi][dj][2] * l2);
            op[3 * EMBED] = f2bf(o[mi][dj][3] * l3);
        }
    }
}

extern "C" void kernel_launch(void* const* d_in, const int* in_sizes, int n_in,
                              void* d_out, int out_size, void* d_ws, size_t ws_size,
                              hipStream_t stream)
{
    const float* x  = (const float*)d_in[0];
    const int* mask = (const int*)d_in[1];
    const float* Wq = (const float*)d_in[2];
    const float* bq = (const float*)d_in[3];
    const float* Wk = (const float*)d_in[4];
    const float* bk = (const float*)d_in[5];
    const float* Wv = (const float*)d_in[6];
    const float* bv = (const float*)d_in[7];
    const float* Wo = (const float*)d_in[8];
    const float* bo = (const float*)d_in[9];
    float* outp = (float*)d_out;

    // Workspace layout (88 MB):
    //   [0,8)   Wt: 4x bf16 1024x1024 (transposed weights)
    //   [8,24)  mask8 (0xFF/0x00)
    //   [24,40) Xb (bf16 x) -- aliased by Ob after qkv consumes Xb
    //   [40,56) Qb  [56,72) Kb  [72,88) Vt (V written pre-transposed by qkv)
    char* ws = (char*)d_ws;
    unsigned short* Wt = (unsigned short*)(ws);
    unsigned char*  m8 = (unsigned char*)(ws + ((size_t)8 << 20));
    unsigned short* Xb = (unsigned short*)(ws + ((size_t)24 << 20));
    unsigned short* Ob = Xb;
    unsigned short* Qb = (unsigned short*)(ws + ((size_t)40 << 20));
    unsigned short* Kb = (unsigned short*)(ws + ((size_t)56 << 20));
    unsigned short* Vt = (unsigned short*)(ws + ((size_t)72 << 20));

    prep_kernel<<<XBLK + MBLK + WBLK, 256, 0, stream>>>(
        x, mask, Wq, Wk, Wv, Wo, Xb, m8, Wt);
    qkv_gemm_kernel<<<1536, 256, 0, stream>>>(
        Xb, Wt, bq, bk, bv, Qb, Kb, Vt);
    attn_mfma_kernel<<<1024, 256, 0, stream>>>(
        Qb, Kb, Vt, m8, Ob);
    out_gemm_kernel<<<512, 256, 0, stream>>>(
        Ob, Wt + (size_t)3 * EMBED * EMBED, bo, outp);
}